// Round 1
// baseline (625.561 us; speedup 1.0000x reference)
//
#include <hip/hip_runtime.h>
#include <hip/hip_bf16.h>
#include <stdint.h>

#define SEQ   2048
#define DIM   4096
#define NH    32
#define NKV   8
#define HD    128
#define NREP  4
#define QKVN  6144   /* 4096 q | 1024 k | 1024 v */
#define KOFF  4096
#define VOFF  5120

typedef __bf16 bf16;
typedef __attribute__((ext_vector_type(8))) __bf16 bf16x8;
typedef __attribute__((ext_vector_type(4))) __bf16 bf16x4;
typedef __attribute__((ext_vector_type(4))) float  f32x4;
typedef __attribute__((address_space(1))) void as1_void;
typedef __attribute__((address_space(3))) void as3_void;

__device__ __forceinline__ void async_copy16(void* lds, const void* g) {
  // LDS dest is wave-uniform base + lane*16; global side may be lane-permuted.
  __builtin_amdgcn_global_load_lds((as1_void*)(void*)g, (as3_void*)lds, 16, 0, 0);
}

__device__ __forceinline__ uint32_t pack2bf(float a, float b) {
  union { bf16 h; uint16_t u; } ca, cb;
  ca.h = (bf16)a; cb.h = (bf16)b;
  return (uint32_t)ca.u | ((uint32_t)cb.u << 16);
}

__device__ __forceinline__ void block_barrier() {
  asm volatile("" ::: "memory");
  __builtin_amdgcn_s_barrier();
  asm volatile("" ::: "memory");
}

// ---------------- elementwise fp32 -> bf16 cast (x) ----------------
__global__ __launch_bounds__(256) void cast_x_kernel(const float* __restrict__ src,
                                                     bf16* __restrict__ dst) {
  size_t i = ((size_t)blockIdx.x * 256 + threadIdx.x) * 4;
  const float4 v = *(const float4*)(src + i);
  bf16x4 o;
  o[0] = (bf16)v.x; o[1] = (bf16)v.y; o[2] = (bf16)v.z; o[3] = (bf16)v.w;
  *(bf16x4*)(dst + i) = o;
}

// ---------------- tiled transpose-cast: 64x64, float4 loads, bf16x4 stores ----------------
__global__ __launch_bounds__(256) void transpose_cast_kernel(const float* __restrict__ src,
                                                             bf16* __restrict__ dst,
                                                             int R, int C) {
  __shared__ float tile[64][65];
  const int c0 = blockIdx.x * 64, r0 = blockIdx.y * 64;
  const int tx = threadIdx.x & 15, ty = threadIdx.x >> 4;   // 16 x 16
#pragma unroll
  for (int p = 0; p < 4; ++p) {
    float4 v = *(const float4*)&src[(size_t)(r0 + ty + p*16) * C + c0 + tx*4];
    tile[ty + p*16][tx*4+0] = v.x;
    tile[ty + p*16][tx*4+1] = v.y;
    tile[ty + p*16][tx*4+2] = v.z;
    tile[ty + p*16][tx*4+3] = v.w;
  }
  __syncthreads();
  const int k = threadIdx.x & 15;   // dst col quad
  const int g = threadIdx.x >> 4;   // dst row group
#pragma unroll
  for (int p = 0; p < 4; ++p) {
    int X = g + 16*p;               // src col = dst row
    bf16x4 o;
    o[0] = (bf16)tile[4*k+0][X];
    o[1] = (bf16)tile[4*k+1][X];
    o[2] = (bf16)tile[4*k+2][X];
    o[3] = (bf16)tile[4*k+3][X];
    *(bf16x4*)&dst[(size_t)(c0 + X) * R + r0 + 4*k] = o;
  }
}

// ---------------- GEMM v3: 256x256 tile, BK=64, 8 waves, 8-phase counted-vmcnt pipeline ----
// C(MxN) = A(MxK) * Bt(NxK)^T, bf16 in, fp32 acc. Per the T2+T3+T4+T5 template:
//  - LDS: 2 buffers x (A 32KB + B 32KB) = 128 KB. Per buffer, per k-slice (K=32):
//    [256 rows][4 x 16B], 16B unit at (row, q) stored at byte row*64 + (q^(row&3))*16.
//    XOR swizzle applied via pre-swizzled GLOBAL source (LDS dest stays lane-linear for
//    global_load_lds); ds_read_b128 then hits every bank exactly 2x (free).
//  - 4 phases per K-tile: (ks,qm) in {0,1}x{0,1}; each phase: ds_read subtile, issue one
//    half-tile stage (2 x global_load_lds/thread), s_barrier, setprio(1), 16 MFMA, setprio(0),
//    s_barrier. Stage schedule: ph0 A-ks1(t+1), ph1 B-ks1(t+1), ph2 A-ks0(t+2), ph3 B-ks0(t+2).
//  - Boundary wait: vmcnt(4) only (the in-flight 4 loads are t+2's ks0 halves, which target
//    regions of buf[t&1] whose reads completed at phase 1). vmcnt(0) only at the tail.
//  Requires NT = K/64 >= 2 (here K = 4096, NT = 64).
template<int OUT_F32, int ROPE>
__global__ __launch_bounds__(512, 2) void gemm256_kernel(const bf16* __restrict__ A,
                                                         const bf16* __restrict__ Bt,
                                                         void* __restrict__ Cout,
                                                         int M, int N, int K,
                                                         const float* __restrict__ fr) {
  __shared__ __align__(16) bf16 As[32768];   // 2 bufs x 32 KB
  __shared__ __align__(16) bf16 Bs[32768];
  char* AsB = (char*)As;
  char* BsB = (char*)Bs;

  const int tid  = threadIdx.x;
  const int w    = tid >> 6, lane = tid & 63;
  const int lane16 = lane & 15, quad = lane >> 4;
  const int wm = w >> 2, wn = w & 3;               // 2(M) x 4(N) wave grid, wave owns 128x64

  // XCD-aware block swizzle (nwg % 8 == 0 at both call sites)
  const int nwg = gridDim.x * gridDim.y;
  int bid = blockIdx.y * gridDim.x + blockIdx.x;
  bid = (bid & 7) * (nwg >> 3) + (bid >> 3);
  const int bx = bid % gridDim.x, by = bid / gridDim.x;
  const int bm = by * 256, bn = bx * 256;

  const int NT = K >> 6;

  // per-lane read bases (swizzled)
  const int qsw = ((quad ^ (lane16 & 3)) << 4);
  const uint32_t aLane = (uint32_t)(wm*128 + lane16) * 64 + qsw;
  const uint32_t bLane = (uint32_t)(wn*64  + lane16) * 64 + qsw;

  // stage one half-tile (one matrix, one k-slice): 1024 16B chunks, 2 per thread.
  // chunk c: row = c>>2, slot = c&3; content = global (rowbase+row, k0+ks*32+((slot^(row&3))*8))
  auto stageA = [&](int buf, int t, int ks) {
#pragma unroll
    for (int i = 0; i < 2; ++i) {
      int c = tid + (i << 9);
      int row = c >> 2;
      int q = ((c & 3) ^ (row & 3)) << 3;
      async_copy16(AsB + buf*32768 + ks*16384 + c*16,
                   A + (size_t)(bm + row) * K + t*64 + ks*32 + q);
    }
  };
  auto stageB = [&](int buf, int t, int ks) {
#pragma unroll
    for (int i = 0; i < 2; ++i) {
      int c = tid + (i << 9);
      int row = c >> 2;
      int q = ((c & 3) ^ (row & 3)) << 3;
      async_copy16(BsB + buf*32768 + ks*16384 + c*16,
                   Bt + (size_t)(bn + row) * K + t*64 + ks*32 + q);
    }
  };

  f32x4 acc[8][4] = {};

#define LD_A(DST, BUF, KS, QM)                                                        \
  do {                                                                                \
    _Pragma("unroll")                                                                 \
    for (int ii = 0; ii < 4; ++ii)                                                    \
      (DST)[ii] = *(const bf16x8*)(AsB + (BUF)*32768 + (KS)*16384 + aLane             \
                                   + ((QM)*4 + ii) * 1024);                           \
  } while (0)
#define LD_B(DST, BUF, KS)                                                            \
  do {                                                                                \
    _Pragma("unroll")                                                                 \
    for (int jj = 0; jj < 4; ++jj)                                                    \
      (DST)[jj] = *(const bf16x8*)(BsB + (BUF)*32768 + (KS)*16384 + bLane             \
                                   + jj * 1024);                                      \
  } while (0)
#define MMA_PHASE(AF, BF, QM)                                                         \
  do {                                                                                \
    __builtin_amdgcn_s_setprio(1);                                                    \
    _Pragma("unroll")                                                                 \
    for (int jj = 0; jj < 4; ++jj)                                                    \
      _Pragma("unroll")                                                               \
      for (int ii = 0; ii < 4; ++ii)                                                  \
        acc[(QM)*4 + ii][jj] = __builtin_amdgcn_mfma_f32_16x16x32_bf16(               \
            (AF)[ii], (BF)[jj], acc[(QM)*4 + ii][jj], 0, 0, 0);                       \
    __builtin_amdgcn_s_setprio(0);                                                    \
  } while (0)

  // prologue: tile 0 fully + tile 1 ks0 halves; wait until tile 0 landed (<=4 outstanding)
  stageA(0, 0, 0); stageB(0, 0, 0); stageA(0, 0, 1); stageB(0, 0, 1);
  stageA(1, 1, 0); stageB(1, 1, 0);
  asm volatile("s_waitcnt vmcnt(4)" ::: "memory");
  block_barrier();

  for (int t = 0; t < NT; ++t) {
    const int cb = t & 1, nb = cb ^ 1;
    bf16x8 af[4], bf0[4], bf1[4];

    // ---- phase 0: ks=0, qm=0 ----
    LD_A(af, cb, 0, 0);
    LD_B(bf0, cb, 0);
    if (t + 1 < NT) stageA(nb, t + 1, 1);
    block_barrier();
    MMA_PHASE(af, bf0, 0);
    block_barrier();

    // ---- phase 1: ks=0, qm=1 ----
    LD_A(af, cb, 0, 1);
    if (t + 1 < NT) stageB(nb, t + 1, 1);
    block_barrier();
    MMA_PHASE(af, bf0, 1);
    block_barrier();

    // ---- phase 2: ks=1, qm=0 ---- (buf cb's ks0 regions are read-free past phase 1)
    LD_A(af, cb, 1, 0);
    LD_B(bf1, cb, 1);
    if (t + 2 < NT) stageA(cb, t + 2, 0);
    block_barrier();
    MMA_PHASE(af, bf1, 0);
    block_barrier();

    // ---- phase 3: ks=1, qm=1 ----
    LD_A(af, cb, 1, 1);
    if (t + 2 < NT) stageB(cb, t + 2, 0);
    block_barrier();
    MMA_PHASE(af, bf1, 1);
    // boundary: guarantee tile t+1 fully landed; keep t+2's ks0 halves (4 loads) in flight
    if (t + 2 < NT) asm volatile("s_waitcnt vmcnt(4)" ::: "memory");
    else            asm volatile("s_waitcnt vmcnt(0)" ::: "memory");
    block_barrier();
  }

  // epilogue: C write (+ optional fused RoPE on cols < 5120)
#pragma unroll
  for (int i = 0; i < 8; ++i)
#pragma unroll
    for (int j = 0; j < 4; ++j) {
      const int colb = bn + wn*64 + j*16;
      const bool do_rope = ROPE && colb < 5120;          // wave-uniform per j
      const int p2 = (colb + lane16) & 126;              // 2*p within head
#pragma unroll
      for (int r = 0; r < 4; ++r) {
        size_t row = (size_t)bm + wm*128 + i*16 + quad*4 + r;  // C/D: row=quad*4+reg
        size_t col = (size_t)colb + lane16;                    //      col=lane&15
        float v = acc[i][j][r];
        if (ROPE) {
          float vp = __shfl_xor(v, 1);                   // partner feature value
          if (do_rope) {
            float2 cd = *(const float2*)&fr[row*128 + p2];
            v = (lane16 & 1) ? (vp*cd.y + v*cd.x) : (v*cd.x - vp*cd.y);
          }
        }
        if (OUT_F32) ((float*)Cout)[row * N + col] = v;
        else         ((bf16*)Cout)[row * N + col] = (bf16)v;
      }
    }
#undef LD_A
#undef LD_B
#undef MMA_PHASE
}

// ---------------- transpose v slice of qkv -> vt[kv][d][t] ----------------
__global__ __launch_bounds__(256) void transpose_v_kernel(const bf16* __restrict__ qkv,
                                                          bf16* __restrict__ vt) {
  __shared__ bf16 tile[32][33];
  int tt = blockIdx.x * 32;
  int dd = blockIdx.y * 32;
  int kv = blockIdx.z;
  int tx = threadIdx.x & 31, ty = threadIdx.x >> 5;
  const bf16* src = qkv + VOFF + kv * HD;
#pragma unroll
  for (int j = 0; j < 4; ++j)
    tile[ty + j*8][tx] = src[(size_t)(tt + ty + j*8) * QKVN + dd + tx];
  __syncthreads();
  bf16* dst = vt + ((size_t)kv * HD + dd) * SEQ + tt;
#pragma unroll
  for (int j = 0; j < 4; ++j)
    dst[(size_t)(ty + j*8) * SEQ + tx] = tile[tx][ty + j*8];
}

// ---------------- flash attention v3 (unchanged) ----------------
__global__ __launch_bounds__(256, 3) void flash_attn_kernel(const bf16* __restrict__ qkv,
                                                            const bf16* __restrict__ vt,
                                                            bf16* __restrict__ out) {
  __shared__ __align__(16) bf16 Ks[4*96*32];    // [kk=4][kvrow=96][32]   24 KB
  __shared__ __align__(16) bf16 Vts[3*128*32];  // [kk2=3][d=128][32kv]   24 KB
  const int b  = blockIdx.x;                    // 1D, qt-descending for balance
  const int qt = 31 - (b >> 5);
  const int h  = b & 31;
  const int kvh = h >> 2;                       // NREP = 4
  const int tid = threadIdx.x;
  const int w = tid >> 6, lane = tid & 63;
  const int lane16 = lane & 15, quad = lane >> 4;
  const float scale = 0.08838834764831845f;     // 1/sqrt(128)
  const int qglob = qt*64 + w*16 + lane16;      // this lane's q column

  const bf16* qrow = qkv + (size_t)qglob * QKVN + h * HD + quad*8;
  bf16x8 qreg[4];
#pragma unroll
  for (int kk = 0; kk < 4; ++kk)
    qreg[kk] = *(const bf16x8*)(qrow + kk*32);

  f32x4 acc_o[8] = {};                          // [jd][reg]: row q=quad*4+reg, col d=jd*16+lane16
  float m_s = -3e38f, l_s = 0.f;                // scalar per lane (column q)

  const bf16* kbase0 = qkv + KOFF + kvh * HD;
  const bf16* vbase0 = vt + (size_t)kvh * HD * SEQ;

  const int L = (qt*64 + 159) / 96;             // ceil((qt+1)*64 / 96) kv tiles
  for (int jj = 0; jj < L; ++jj) {
    const int kv0 = jj * 96;
    __syncthreads();                            // prior iter's ds_reads done before restage
#pragma unroll
    for (int i = 0; i < 6; ++i) {               // 1536 chunks each for K and Vt
      int c = tid + i * 256;
      {
        int kk = c / 384, rem = c - kk*384;     // K: [kk][kvrow][32]
        async_copy16(&Ks[c*8], kbase0 + (size_t)(kv0 + (rem >> 2)) * QKVN + kk*32 + (rem & 3) * 8);
      }
      {
        int kk2 = c >> 9, cp = c & 511;         // Vt: [kk2][d][32kv]
        async_copy16(&Vts[c*8], vbase0 + (size_t)(cp >> 2) * SEQ + kv0 + kk2*32 + (cp & 3) * 8);
      }
    }
    __syncthreads();                            // drains staging

    // S^T = K Q^T : A=K rows (m=kv), B=Q rows (n=q). acc row=kv local, col=q.
    f32x4 accT[6] = {};
#pragma unroll
    for (int kk = 0; kk < 4; ++kk)
#pragma unroll
      for (int jn = 0; jn < 6; ++jn) {
        bf16x8 kf = *(const bf16x8*)&Ks[(kk*96 + jn*16 + lane16)*32 + quad*8];
        accT[jn] = __builtin_amdgcn_mfma_f32_16x16x32_bf16(kf, qreg[kk], accT[jn], 0, 0, 0);
      }

    float s[6][4];
#pragma unroll
    for (int jn = 0; jn < 6; ++jn)
#pragma unroll
      for (int r = 0; r < 4; ++r) {
        float v = accT[jn][r] * scale;
        if ((kv0 + jn*16 + quad*4 + r) > qglob) v = -3e38f;
        s[jn][r] = v;
      }

    float mt = s[0][0];
#pragma unroll
    for (int jn = 0; jn < 6; ++jn)
#pragma unroll
      for (int r = 0; r < 4; ++r) mt = fmaxf(mt, s[jn][r]);
    mt = fmaxf(mt, __shfl_xor(mt, 16));
    mt = fmaxf(mt, __shfl_xor(mt, 32));
    float mnew = fmaxf(m_s, mt);
    float alpha = __expf(m_s - mnew);
    m_s = mnew;
    float rs = 0.f;
#pragma unroll
    for (int jn = 0; jn < 6; ++jn)
#pragma unroll
      for (int r = 0; r < 4; ++r) {
        float p = __expf(s[jn][r] - mnew);
        s[jn][r] = p;
        rs += p;
      }
    rs += __shfl_xor(rs, 16);
    rs += __shfl_xor(rs, 32);
    l_s = l_s * alpha + rs;

    float alpha_row[4];
#pragma unroll
    for (int r = 0; r < 4; ++r)
      alpha_row[r] = __shfl(alpha, quad*4 + r);
#pragma unroll
    for (int jd = 0; jd < 8; ++jd)
#pragma unroll
      for (int r = 0; r < 4; ++r) acc_o[jd][r] *= alpha_row[r];

    uint32_t pk[6][2];
#pragma unroll
    for (int jn = 0; jn < 6; ++jn) {
      pk[jn][0] = pack2bf(s[jn][0], s[jn][1]);
      pk[jn][1] = pack2bf(s[jn][2], s[jn][3]);
    }

    const int src0 = (quad & 1) * 32 + lane16;
    const int src1 = src0 + 16;
    const bool hi = quad >= 2;
#pragma unroll
    for (int kk2 = 0; kk2 < 3; ++kk2) {
      uint32_t v0l = __shfl(pk[2*kk2][0],   src0), v0h = __shfl(pk[2*kk2][1],   src0);
      uint32_t v1l = __shfl(pk[2*kk2][0],   src1), v1h = __shfl(pk[2*kk2][1],   src1);
      uint32_t w0l = __shfl(pk[2*kk2+1][0], src0), w0h = __shfl(pk[2*kk2+1][1], src0);
      uint32_t w1l = __shfl(pk[2*kk2+1][0], src1), w1h = __shfl(pk[2*kk2+1][1], src1);
      union { uint32_t u[4]; bf16x8 v; } af;
      af.u[0] = hi ? w0l : v0l;
      af.u[1] = hi ? w0h : v0h;
      af.u[2] = hi ? w1l : v1l;
      af.u[3] = hi ? w1h : v1h;
#pragma unroll
      for (int jd = 0; jd < 8; ++jd) {
        bf16x8 vf = *(const bf16x8*)&Vts[(kk2*128 + jd*16 + lane16)*32 + quad*8];
        acc_o[jd] = __builtin_amdgcn_mfma_f32_16x16x32_bf16(af.v, vf, acc_o[jd], 0, 0, 0);
      }
    }
  }

  const float inv_l = 1.f / l_s;
  float linv[4];
#pragma unroll
  for (int r = 0; r < 4; ++r)
    linv[r] = __shfl(inv_l, quad*4 + r);

  bf16* obase = out + (size_t)(qt*64 + w*16) * DIM + h * HD;
#pragma unroll
  for (int jd = 0; jd < 8; ++jd)
#pragma unroll
    for (int r = 0; r < 4; ++r)
      obase[(size_t)(quad*4 + r) * DIM + jd*16 + lane16] = (bf16)(acc_o[jd][r] * linv[r]);
}

extern "C" void kernel_launch(void* const* d_in, const int* in_sizes, int n_in,
                              void* d_out, int out_size, void* d_ws, size_t ws_size,
                              hipStream_t stream) {
  const float* x  = (const float*)d_in[0];
  // d_in[1] = cache_kv: dead (start_pos=0, L=SEQ -> keys/values == xk/xv)
  const float* fr = (const float*)d_in[2];
  const float* wq = (const float*)d_in[3];
  const float* wk = (const float*)d_in[4];
  const float* wv = (const float*)d_in[5];
  const float* wo = (const float*)d_in[6];
  // d_in[7] = start_pos = 0
  float* out = (float*)d_out;

  char* ws = (char*)d_ws;
  bf16* xb     = (bf16*)(ws);                    // 2048x4096          16,777,216 B
  bf16* wqkv_t = (bf16*)(ws + 16777216);         // 6144x4096 (N,K)   50,331,648 B
  bf16* wo_t   = (bf16*)(ws + 67108864);         // 4096x4096 (N,K)   33,554,432 B
  bf16* qkv    = (bf16*)(ws + 100663296);        // 2048x6144         25,165,824 B
  bf16* vt     = (bf16*)(ws + 125829120);        // 8x128x2048         4,194,304 B
  bf16* attn   = (bf16*)(ws + 130023424);        // 2048x4096         16,777,216 B
  (void)ws_size; (void)in_sizes; (void)n_in; (void)out_size;

  cast_x_kernel<<<8192, 256, 0, stream>>>(x, xb);
  transpose_cast_kernel<<<dim3(64,64), 256, 0, stream>>>(wq, wqkv_t, DIM, DIM);
  transpose_cast_kernel<<<dim3(16,64), 256, 0, stream>>>(wk, wqkv_t + (size_t)4096*4096, DIM, 1024);
  transpose_cast_kernel<<<dim3(16,64), 256, 0, stream>>>(wv, wqkv_t + (size_t)5120*4096, DIM, 1024);
  transpose_cast_kernel<<<dim3(64,64), 256, 0, stream>>>(wo, wo_t, DIM, DIM);

  gemm256_kernel<0,1><<<dim3(24,8), 512, 0, stream>>>(xb, wqkv_t, qkv, SEQ, QKVN, DIM, fr);
  transpose_v_kernel<<<dim3(64,4,8), 256, 0, stream>>>(qkv, vt);
  flash_attn_kernel<<<1024, 256, 0, stream>>>(qkv, vt, attn);
  gemm256_kernel<1,0><<<dim3(16,8), 512, 0, stream>>>(attn, wo_t, out, SEQ, DIM, DIM, nullptr);
}

// Round 2
// 621.080 us; speedup vs baseline: 1.0072x; 1.0072x over previous
//
#include <hip/hip_runtime.h>
#include <hip/hip_bf16.h>
#include <stdint.h>

#define SEQ   2048
#define DIM   4096
#define NH    32
#define NKV   8
#define HD    128
#define NREP  4
#define QKVN  6144   /* 4096 q | 1024 k | 1024 v */
#define KOFF  4096
#define VOFF  5120

typedef __bf16 bf16;
typedef __attribute__((ext_vector_type(8))) __bf16 bf16x8;
typedef __attribute__((ext_vector_type(4))) __bf16 bf16x4;
typedef __attribute__((ext_vector_type(4))) float  f32x4;
typedef __attribute__((address_space(1))) void as1_void;
typedef __attribute__((address_space(3))) void as3_void;

__device__ __forceinline__ void async_copy16(void* lds, const void* g) {
  // LDS dest is wave-uniform base + lane*16; global side may be lane-permuted.
  __builtin_amdgcn_global_load_lds((as1_void*)(void*)g, (as3_void*)lds, 16, 0, 0);
}

__device__ __forceinline__ uint32_t pack2bf(float a, float b) {
  union { bf16 h; uint16_t u; } ca, cb;
  ca.h = (bf16)a; cb.h = (bf16)b;
  return (uint32_t)ca.u | ((uint32_t)cb.u << 16);
}

__device__ __forceinline__ void block_barrier() {
  asm volatile("" ::: "memory");
  __builtin_amdgcn_s_barrier();
  asm volatile("" ::: "memory");
}

// ---------------- elementwise fp32 -> bf16 cast (x) ----------------
__global__ __launch_bounds__(256) void cast_x_kernel(const float* __restrict__ src,
                                                     bf16* __restrict__ dst) {
  size_t i = ((size_t)blockIdx.x * 256 + threadIdx.x) * 4;
  const float4 v = *(const float4*)(src + i);
  bf16x4 o;
  o[0] = (bf16)v.x; o[1] = (bf16)v.y; o[2] = (bf16)v.z; o[3] = (bf16)v.w;
  *(bf16x4*)(dst + i) = o;
}

// ---------------- tiled transpose-cast: 64x64, float4 loads, bf16x4 stores ----------------
__global__ __launch_bounds__(256) void transpose_cast_kernel(const float* __restrict__ src,
                                                             bf16* __restrict__ dst,
                                                             int R, int C) {
  __shared__ float tile[64][65];
  const int c0 = blockIdx.x * 64, r0 = blockIdx.y * 64;
  const int tx = threadIdx.x & 15, ty = threadIdx.x >> 4;   // 16 x 16
#pragma unroll
  for (int p = 0; p < 4; ++p) {
    float4 v = *(const float4*)&src[(size_t)(r0 + ty + p*16) * C + c0 + tx*4];
    tile[ty + p*16][tx*4+0] = v.x;
    tile[ty + p*16][tx*4+1] = v.y;
    tile[ty + p*16][tx*4+2] = v.z;
    tile[ty + p*16][tx*4+3] = v.w;
  }
  __syncthreads();
  const int k = threadIdx.x & 15;   // dst col quad
  const int g = threadIdx.x >> 4;   // dst row group
#pragma unroll
  for (int p = 0; p < 4; ++p) {
    int X = g + 16*p;               // src col = dst row
    bf16x4 o;
    o[0] = (bf16)tile[4*k+0][X];
    o[1] = (bf16)tile[4*k+1][X];
    o[2] = (bf16)tile[4*k+2][X];
    o[3] = (bf16)tile[4*k+3][X];
    *(bf16x4*)&dst[(size_t)(c0 + X) * R + r0 + 4*k] = o;
  }
}

// ---------------- GEMM v4: BM=256 x BN tile, BK=64, 8 waves, 4-phase counted-vmcnt ----
// C(MxN) = A(MxK) * Bt(NxK)^T, bf16 in, fp32 acc.
//  - Grid sized for EXACT 256 blocks (1/CU): QKV uses BN=192 (8x32), WO uses BN=128 (8x32).
//  - LDS fragment-major layout, conflict-free by construction (no swizzle):
//      A: [buf][ks][q][row][16B]  (q = k-quad 0..3, row 0..255)  2 x 32 KB
//      B: [buf][ks][q][col][16B]  (col 0..BN-1)                  2 x BN*128 B
//    Reads: 16 lanes (lane16) hit 256B contiguous; quad groups at 128B-aligned offsets
//    -> every ds_read_b128 touches each bank exactly 2x (free). global_load_lds dest is
//    lane-linear; the (q,row) decomposition is folded into the per-lane GLOBAL address.
//  - Staging granularity: A = k-slice (2 chunks/thread), B = full K-tile (BN/64 chunks/thread).
//    Per tile t: ph0 issues A(t+1,ks1); ph2 issues A(t+2,ks0); ph3 issues B(t+2).
//    Waits: vmcnt(4+BN/64) at end-of-ph1 (guards A(t)ks1, issued 5 phases prior) and
//    end-of-ph3 (guards A(t+1)ks0/B(t+1), issued 4-5 phases prior). vmcnt->0 only at tail.
template<int OUT_F32, int ROPE, int BN>
__global__ __launch_bounds__(512, 2) void gemm256_kernel(const bf16* __restrict__ A,
                                                         const bf16* __restrict__ Bt,
                                                         void* __restrict__ Cout,
                                                         int M, int N, int K,
                                                         const float* __restrict__ fr) {
  constexpr int BNF = BN / 64;            // B fragments per wave (wave owns BN/4 cols)
  constexpr int BCH = BN / 64;            // B full-tile chunks per thread
  constexpr int BBYTES = BN * 128;        // one B buffer (BN x 64 x 2B)
  __shared__ __align__(16) char lds[65536 + 2 * BBYTES];

  const int tid  = threadIdx.x;
  const int w    = tid >> 6, lane = tid & 63;
  const int lane16 = lane & 15, quad = lane >> 4;
  const int wm = w >> 2, wn = w & 3;               // 2(M) x 4(N) wave grid

  // XCD-aware block swizzle (grid is exactly 256 = 8*32 blocks)
  const int nwg = gridDim.x * gridDim.y;
  int bid = blockIdx.y * gridDim.x + blockIdx.x;
  bid = (bid & 7) * (nwg >> 3) + (bid >> 3);
  const int bx = bid % gridDim.x, by = bid / gridDim.x;
  const int bm = by * 256, bn = bx * BN;

  const int NT = K >> 6;

  // stage one A k-slice: 1024 chunks, 2/thread. chunk c -> (q=c>>8, row=c&255),
  // LDS linear at c*16 within the slice region.
  auto stageA = [&](int buf, int t, int ks) {
#pragma unroll
    for (int i = 0; i < 2; ++i) {
      int c = tid + (i << 9);
      int q = c >> 8, row = c & 255;
      async_copy16(lds + buf*32768 + ks*16384 + c*16,
                   A + (size_t)(bm + row) * K + t*64 + ks*32 + q*8);
    }
  };
  // stage full B K-tile: BN*8 chunks, BCH/thread. chunk c -> (ks, q, col).
  auto stageB = [&](int buf, int t) {
#pragma unroll
    for (int i = 0; i < BCH; ++i) {
      int c = tid + (i << 9);
      int ks = c / (BN*4), r = c - ks*(BN*4);
      int q = r / BN, col = r - q*BN;
      async_copy16(lds + 65536 + buf*BBYTES + c*16,
                   Bt + (size_t)(bn + col) * K + t*64 + ks*32 + q*8);
    }
  };

  f32x4 acc[8][BNF] = {};

#define LD_A(DST, BUF, KS, QM)                                                        \
  do {                                                                                \
    _Pragma("unroll")                                                                 \
    for (int ii = 0; ii < 4; ++ii)                                                    \
      (DST)[ii] = *(const bf16x8*)(lds + (BUF)*32768 + (KS)*16384 +                   \
          (quad*256 + wm*128 + (QM)*64 + ii*16 + lane16) * 16);                       \
  } while (0)
#define LD_B(DST, BUF, KS)                                                            \
  do {                                                                                \
    _Pragma("unroll")                                                                 \
    for (int jj = 0; jj < BNF; ++jj)                                                  \
      (DST)[jj] = *(const bf16x8*)(lds + 65536 + (BUF)*BBYTES +                       \
          (((KS)*4 + quad)*BN + wn*(BN/4) + jj*16 + lane16) * 16);                    \
  } while (0)
#define MMA_PHASE(AF, BF, QM)                                                         \
  do {                                                                                \
    asm volatile("s_waitcnt lgkmcnt(0)" ::: "memory");                                \
    __builtin_amdgcn_sched_barrier(0);                                                \
    __builtin_amdgcn_s_setprio(1);                                                    \
    _Pragma("unroll")                                                                 \
    for (int jj = 0; jj < BNF; ++jj)                                                  \
      _Pragma("unroll")                                                               \
      for (int ii = 0; ii < 4; ++ii)                                                  \
        acc[(QM)*4 + ii][jj] = __builtin_amdgcn_mfma_f32_16x16x32_bf16(               \
            (AF)[ii], (BF)[jj], acc[(QM)*4 + ii][jj], 0, 0, 0);                       \
    __builtin_amdgcn_s_setprio(0);                                                    \
  } while (0)
#define VM_WAIT_STEADY()                                                              \
  do {                                                                                \
    if constexpr (BN == 192) asm volatile("s_waitcnt vmcnt(7)" ::: "memory");         \
    else                     asm volatile("s_waitcnt vmcnt(6)" ::: "memory");         \
  } while (0)

  // prologue: tile0 (A ks0, B, A ks1) + tile1 (A ks0, B). Tile1's A ks1 is issued by
  // tile0's phase 0. Wait: everything through B(0) landed -> keep 4+BCH newest.
  stageA(0, 0, 0); stageB(0, 0); stageA(0, 0, 1);
  stageA(1, 1, 0); stageB(1, 1);
  VM_WAIT_STEADY();
  block_barrier();

  for (int t = 0; t < NT; ++t) {
    const int cb = t & 1, nb = cb ^ 1;
    bf16x8 af[4], bf0[BNF], bf1[BNF];

    // ---- phase 0: ks=0, qm=0 ----
    LD_A(af, cb, 0, 0);
    LD_B(bf0, cb, 0);
    if (t + 1 < NT) stageA(nb, t + 1, 1);
    block_barrier();
    MMA_PHASE(af, bf0, 0);
    block_barrier();

    // ---- phase 1: ks=0, qm=1 ----
    LD_A(af, cb, 0, 1);
    block_barrier();
    MMA_PHASE(af, bf0, 1);
    // guard phase 2's reads of A(t)ks1 (issued 5 phases ago)
    if (t + 1 < NT) VM_WAIT_STEADY();
    else            asm volatile("s_waitcnt vmcnt(0)" ::: "memory");
    block_barrier();

    // ---- phase 2: ks=1, qm=0 ---- (cb.A.ks0 consumed through phase 1)
    LD_A(af, cb, 1, 0);
    LD_B(bf1, cb, 1);
    if (t + 2 < NT) stageA(cb, t + 2, 0);
    block_barrier();
    MMA_PHASE(af, bf1, 0);
    block_barrier();

    // ---- phase 3: ks=1, qm=1 ---- (cb.B fully consumed after phase 2)
    LD_A(af, cb, 1, 1);
    if (t + 2 < NT) stageB(cb, t + 2);
    block_barrier();
    MMA_PHASE(af, bf1, 1);
    // guard next tile's reads of A(t+1)ks0 / B(t+1) (issued 4-5 phases ago)
    if (t + 2 < NT)      VM_WAIT_STEADY();
    else if (t + 1 < NT) asm volatile("s_waitcnt vmcnt(2)" ::: "memory");
    else                 asm volatile("s_waitcnt vmcnt(0)" ::: "memory");
    block_barrier();
  }

  // epilogue: C write (+ optional fused RoPE on cols < 5120)
#pragma unroll
  for (int i = 0; i < 8; ++i)
#pragma unroll
    for (int j = 0; j < BNF; ++j) {
      const int colb = bn + wn*(BN/4) + j*16;
      const bool do_rope = ROPE && colb < 5120;          // wave-uniform per j
      const int p2 = (colb + lane16) & 126;              // 2*p within head
#pragma unroll
      for (int r = 0; r < 4; ++r) {
        size_t row = (size_t)bm + wm*128 + i*16 + quad*4 + r;  // C/D: row=quad*4+reg
        size_t col = (size_t)colb + lane16;                    //      col=lane&15
        float v = acc[i][j][r];
        if (ROPE) {
          float vp = __shfl_xor(v, 1);                   // partner feature value
          if (do_rope) {
            float2 cd = *(const float2*)&fr[row*128 + p2];
            v = (lane16 & 1) ? (vp*cd.y + v*cd.x) : (v*cd.x - vp*cd.y);
          }
        }
        if (OUT_F32) ((float*)Cout)[row * N + col] = v;
        else         ((bf16*)Cout)[row * N + col] = (bf16)v;
      }
    }
#undef LD_A
#undef LD_B
#undef MMA_PHASE
#undef VM_WAIT_STEADY
}

// ---------------- transpose v slice of qkv -> vt[kv][d][t] ----------------
__global__ __launch_bounds__(256) void transpose_v_kernel(const bf16* __restrict__ qkv,
                                                          bf16* __restrict__ vt) {
  __shared__ bf16 tile[32][33];
  int tt = blockIdx.x * 32;
  int dd = blockIdx.y * 32;
  int kv = blockIdx.z;
  int tx = threadIdx.x & 31, ty = threadIdx.x >> 5;
  const bf16* src = qkv + VOFF + kv * HD;
#pragma unroll
  for (int j = 0; j < 4; ++j)
    tile[ty + j*8][tx] = src[(size_t)(tt + ty + j*8) * QKVN + dd + tx];
  __syncthreads();
  bf16* dst = vt + ((size_t)kv * HD + dd) * SEQ + tt;
#pragma unroll
  for (int j = 0; j < 4; ++j)
    dst[(size_t)(ty + j*8) * SEQ + tx] = tile[tx][ty + j*8];
}

// ---------------- flash attention v3 (unchanged) ----------------
__global__ __launch_bounds__(256, 3) void flash_attn_kernel(const bf16* __restrict__ qkv,
                                                            const bf16* __restrict__ vt,
                                                            bf16* __restrict__ out) {
  __shared__ __align__(16) bf16 Ks[4*96*32];    // [kk=4][kvrow=96][32]   24 KB
  __shared__ __align__(16) bf16 Vts[3*128*32];  // [kk2=3][d=128][32kv]   24 KB
  const int b  = blockIdx.x;                    // 1D, qt-descending for balance
  const int qt = 31 - (b >> 5);
  const int h  = b & 31;
  const int kvh = h >> 2;                       // NREP = 4
  const int tid = threadIdx.x;
  const int w = tid >> 6, lane = tid & 63;
  const int lane16 = lane & 15, quad = lane >> 4;
  const float scale = 0.08838834764831845f;     // 1/sqrt(128)
  const int qglob = qt*64 + w*16 + lane16;      // this lane's q column

  const bf16* qrow = qkv + (size_t)qglob * QKVN + h * HD + quad*8;
  bf16x8 qreg[4];
#pragma unroll
  for (int kk = 0; kk < 4; ++kk)
    qreg[kk] = *(const bf16x8*)(qrow + kk*32);

  f32x4 acc_o[8] = {};                          // [jd][reg]: row q=quad*4+reg, col d=jd*16+lane16
  float m_s = -3e38f, l_s = 0.f;                // scalar per lane (column q)

  const bf16* kbase0 = qkv + KOFF + kvh * HD;
  const bf16* vbase0 = vt + (size_t)kvh * HD * SEQ;

  const int L = (qt*64 + 159) / 96;             // ceil((qt+1)*64 / 96) kv tiles
  for (int jj = 0; jj < L; ++jj) {
    const int kv0 = jj * 96;
    __syncthreads();                            // prior iter's ds_reads done before restage
#pragma unroll
    for (int i = 0; i < 6; ++i) {               // 1536 chunks each for K and Vt
      int c = tid + i * 256;
      {
        int kk = c / 384, rem = c - kk*384;     // K: [kk][kvrow][32]
        async_copy16(&Ks[c*8], kbase0 + (size_t)(kv0 + (rem >> 2)) * QKVN + kk*32 + (rem & 3) * 8);
      }
      {
        int kk2 = c >> 9, cp = c & 511;         // Vt: [kk2][d][32kv]
        async_copy16(&Vts[c*8], vbase0 + (size_t)(cp >> 2) * SEQ + kv0 + kk2*32 + (cp & 3) * 8);
      }
    }
    __syncthreads();                            // drains staging

    // S^T = K Q^T : A=K rows (m=kv), B=Q rows (n=q). acc row=kv local, col=q.
    f32x4 accT[6] = {};
#pragma unroll
    for (int kk = 0; kk < 4; ++kk)
#pragma unroll
      for (int jn = 0; jn < 6; ++jn) {
        bf16x8 kf = *(const bf16x8*)&Ks[(kk*96 + jn*16 + lane16)*32 + quad*8];
        accT[jn] = __builtin_amdgcn_mfma_f32_16x16x32_bf16(kf, qreg[kk], accT[jn], 0, 0, 0);
      }

    float s[6][4];
#pragma unroll
    for (int jn = 0; jn < 6; ++jn)
#pragma unroll
      for (int r = 0; r < 4; ++r) {
        float v = accT[jn][r] * scale;
        if ((kv0 + jn*16 + quad*4 + r) > qglob) v = -3e38f;
        s[jn][r] = v;
      }

    float mt = s[0][0];
#pragma unroll
    for (int jn = 0; jn < 6; ++jn)
#pragma unroll
      for (int r = 0; r < 4; ++r) mt = fmaxf(mt, s[jn][r]);
    mt = fmaxf(mt, __shfl_xor(mt, 16));
    mt = fmaxf(mt, __shfl_xor(mt, 32));
    float mnew = fmaxf(m_s, mt);
    float alpha = __expf(m_s - mnew);
    m_s = mnew;
    float rs = 0.f;
#pragma unroll
    for (int jn = 0; jn < 6; ++jn)
#pragma unroll
      for (int r = 0; r < 4; ++r) {
        float p = __expf(s[jn][r] - mnew);
        s[jn][r] = p;
        rs += p;
      }
    rs += __shfl_xor(rs, 16);
    rs += __shfl_xor(rs, 32);
    l_s = l_s * alpha + rs;

    float alpha_row[4];
#pragma unroll
    for (int r = 0; r < 4; ++r)
      alpha_row[r] = __shfl(alpha, quad*4 + r);
#pragma unroll
    for (int jd = 0; jd < 8; ++jd)
#pragma unroll
      for (int r = 0; r < 4; ++r) acc_o[jd][r] *= alpha_row[r];

    uint32_t pk[6][2];
#pragma unroll
    for (int jn = 0; jn < 6; ++jn) {
      pk[jn][0] = pack2bf(s[jn][0], s[jn][1]);
      pk[jn][1] = pack2bf(s[jn][2], s[jn][3]);
    }

    const int src0 = (quad & 1) * 32 + lane16;
    const int src1 = src0 + 16;
    const bool hi = quad >= 2;
#pragma unroll
    for (int kk2 = 0; kk2 < 3; ++kk2) {
      uint32_t v0l = __shfl(pk[2*kk2][0],   src0), v0h = __shfl(pk[2*kk2][1],   src0);
      uint32_t v1l = __shfl(pk[2*kk2][0],   src1), v1h = __shfl(pk[2*kk2][1],   src1);
      uint32_t w0l = __shfl(pk[2*kk2+1][0], src0), w0h = __shfl(pk[2*kk2+1][1], src0);
      uint32_t w1l = __shfl(pk[2*kk2+1][0], src1), w1h = __shfl(pk[2*kk2+1][1], src1);
      union { uint32_t u[4]; bf16x8 v; } af;
      af.u[0] = hi ? w0l : v0l;
      af.u[1] = hi ? w0h : v0h;
      af.u[2] = hi ? w1l : v1l;
      af.u[3] = hi ? w1h : v1h;
#pragma unroll
      for (int jd = 0; jd < 8; ++jd) {
        bf16x8 vf = *(const bf16x8*)&Vts[(kk2*128 + jd*16 + lane16)*32 + quad*8];
        acc_o[jd] = __builtin_amdgcn_mfma_f32_16x16x32_bf16(af.v, vf, acc_o[jd], 0, 0, 0);
      }
    }
  }

  const float inv_l = 1.f / l_s;
  float linv[4];
#pragma unroll
  for (int r = 0; r < 4; ++r)
    linv[r] = __shfl(inv_l, quad*4 + r);

  bf16* obase = out + (size_t)(qt*64 + w*16) * DIM + h * HD;
#pragma unroll
  for (int jd = 0; jd < 8; ++jd)
#pragma unroll
    for (int r = 0; r < 4; ++r)
      obase[(size_t)(quad*4 + r) * DIM + jd*16 + lane16] = (bf16)(acc_o[jd][r] * linv[r]);
}

extern "C" void kernel_launch(void* const* d_in, const int* in_sizes, int n_in,
                              void* d_out, int out_size, void* d_ws, size_t ws_size,
                              hipStream_t stream) {
  const float* x  = (const float*)d_in[0];
  // d_in[1] = cache_kv: dead (start_pos=0, L=SEQ -> keys/values == xk/xv)
  const float* fr = (const float*)d_in[2];
  const float* wq = (const float*)d_in[3];
  const float* wk = (const float*)d_in[4];
  const float* wv = (const float*)d_in[5];
  const float* wo = (const float*)d_in[6];
  // d_in[7] = start_pos = 0
  float* out = (float*)d_out;

  char* ws = (char*)d_ws;
  bf16* xb     = (bf16*)(ws);                    // 2048x4096          16,777,216 B
  bf16* wqkv_t = (bf16*)(ws + 16777216);         // 6144x4096 (N,K)   50,331,648 B
  bf16* wo_t   = (bf16*)(ws + 67108864);         // 4096x4096 (N,K)   33,554,432 B
  bf16* qkv    = (bf16*)(ws + 100663296);        // 2048x6144         25,165,824 B
  bf16* vt     = (bf16*)(ws + 125829120);        // 8x128x2048         4,194,304 B
  bf16* attn   = (bf16*)(ws + 130023424);        // 2048x4096         16,777,216 B
  (void)ws_size; (void)in_sizes; (void)n_in; (void)out_size;

  cast_x_kernel<<<8192, 256, 0, stream>>>(x, xb);
  transpose_cast_kernel<<<dim3(64,64), 256, 0, stream>>>(wq, wqkv_t, DIM, DIM);
  transpose_cast_kernel<<<dim3(16,64), 256, 0, stream>>>(wk, wqkv_t + (size_t)4096*4096, DIM, 1024);
  transpose_cast_kernel<<<dim3(16,64), 256, 0, stream>>>(wv, wqkv_t + (size_t)5120*4096, DIM, 1024);
  transpose_cast_kernel<<<dim3(64,64), 256, 0, stream>>>(wo, wo_t, DIM, DIM);

  gemm256_kernel<0,1,192><<<dim3(32,8), 512, 0, stream>>>(xb, wqkv_t, qkv, SEQ, QKVN, DIM, fr);
  transpose_v_kernel<<<dim3(64,4,8), 256, 0, stream>>>(qkv, vt);
  flash_attn_kernel<<<1024, 256, 0, stream>>>(qkv, vt, attn);
  gemm256_kernel<1,0,128><<<dim3(32,8), 512, 0, stream>>>(attn, wo_t, out, SEQ, DIM, DIM, nullptr);
}

// Round 3
// 581.469 us; speedup vs baseline: 1.0758x; 1.0681x over previous
//
#include <hip/hip_runtime.h>
#include <hip/hip_bf16.h>
#include <stdint.h>

#define SEQ   2048
#define DIM   4096
#define NH    32
#define NKV   8
#define HD    128
#define NREP  4
#define QKVN  6144   /* 4096 q | 1024 k | 1024 v */
#define KOFF  4096
#define VOFF  5120

typedef __bf16 bf16;
typedef __attribute__((ext_vector_type(8))) __bf16 bf16x8;
typedef __attribute__((ext_vector_type(4))) __bf16 bf16x4;
typedef __attribute__((ext_vector_type(4))) float  f32x4;
typedef __attribute__((address_space(1))) void as1_void;
typedef __attribute__((address_space(3))) void as3_void;

__device__ __forceinline__ void async_copy16(void* lds, const void* g) {
  // LDS dest is wave-uniform base + lane*16; global side may be lane-permuted.
  __builtin_amdgcn_global_load_lds((as1_void*)(void*)g, (as3_void*)lds, 16, 0, 0);
}

__device__ __forceinline__ uint32_t pack2bf(float a, float b) {
  union { bf16 h; uint16_t u; } ca, cb;
  ca.h = (bf16)a; cb.h = (bf16)b;
  return (uint32_t)ca.u | ((uint32_t)cb.u << 16);
}

__device__ __forceinline__ void block_barrier() {
  asm volatile("" ::: "memory");
  __builtin_amdgcn_s_barrier();
  asm volatile("" ::: "memory");
}

// ---------------- elementwise fp32 -> bf16 cast (x) ----------------
__global__ __launch_bounds__(256) void cast_x_kernel(const float* __restrict__ src,
                                                     bf16* __restrict__ dst) {
  size_t i = ((size_t)blockIdx.x * 256 + threadIdx.x) * 4;
  const float4 v = *(const float4*)(src + i);
  bf16x4 o;
  o[0] = (bf16)v.x; o[1] = (bf16)v.y; o[2] = (bf16)v.z; o[3] = (bf16)v.w;
  *(bf16x4*)(dst + i) = o;
}

// ---------------- tiled transpose-cast: 64x64, float4 loads, bf16x4 stores ----------------
__global__ __launch_bounds__(256) void transpose_cast_kernel(const float* __restrict__ src,
                                                             bf16* __restrict__ dst,
                                                             int R, int C) {
  __shared__ float tile[64][65];
  const int c0 = blockIdx.x * 64, r0 = blockIdx.y * 64;
  const int tx = threadIdx.x & 15, ty = threadIdx.x >> 4;   // 16 x 16
#pragma unroll
  for (int p = 0; p < 4; ++p) {
    float4 v = *(const float4*)&src[(size_t)(r0 + ty + p*16) * C + c0 + tx*4];
    tile[ty + p*16][tx*4+0] = v.x;
    tile[ty + p*16][tx*4+1] = v.y;
    tile[ty + p*16][tx*4+2] = v.z;
    tile[ty + p*16][tx*4+3] = v.w;
  }
  __syncthreads();
  const int k = threadIdx.x & 15;   // dst col quad
  const int g = threadIdx.x >> 4;   // dst row group
#pragma unroll
  for (int p = 0; p < 4; ++p) {
    int X = g + 16*p;               // src col = dst row
    bf16x4 o;
    o[0] = (bf16)tile[4*k+0][X];
    o[1] = (bf16)tile[4*k+1][X];
    o[2] = (bf16)tile[4*k+2][X];
    o[3] = (bf16)tile[4*k+3][X];
    *(bf16x4*)&dst[(size_t)(c0 + X) * R + r0 + 4*k] = o;
  }
}

// ---------------- GEMM v5: BM=256 x BN, BK=64, 8 waves, loose 2-barrier counted-vmcnt ----
// C(MxN) = A(MxK) * Bt(NxK)^T, bf16 in, fp32 acc. Grid = exactly 256 blocks (1/CU).
//  - LDS layout per tile: [row][8 slots x 16B] (128 B rows), slot-XOR swizzle:
//    phys slot sl holds global k-chunk (sl ^ (row&7)). Staging chunk c -> row=c>>3, sl=c&7:
//    8 consecutive lanes read one row's 128 B (fully coalesced, 16 lines/instr), LDS dest
//    stays lane-linear (c*16). Frag read (ks,quad): S=((ks*4+quad)^(lane16&7)) -> banks
//    covered exactly 2x per ds_read_b128 (free, no conflicts).
//  - A double-buffered (2x32 KB), staged LATE (after the all-reads-done barrier; A panel is
//    XCD-L2-resident so 1-tile distance suffices). B triple-buffered (3 x BN*128 B), staged
//    at tile START (2-tile distance; B streams from L3). Total LDS 136 KB (BN=192) / 112 KB.
//  - ONE vmcnt per tile: vmcnt(4+BCH) keeps the newest {A(t+2),B(t+2)} in flight, drains
//    {A(t+1),B(t+1)}. vmcnt(0) only in the last two tiles. 2 barriers per tile.
template<int OUT_F32, int ROPE, int BN>
__global__ __launch_bounds__(512, 2) void gemm256_kernel(const bf16* __restrict__ A,
                                                         const bf16* __restrict__ Bt,
                                                         void* __restrict__ Cout,
                                                         int M, int N, int K,
                                                         const float* __restrict__ fr) {
  constexpr int BNF = BN / 64;            // B fragments per wave (wave owns BN/4 cols)
  constexpr int BCH = BN / 64;            // B tile chunks per thread (BN*8 / 512)
  constexpr int BBUF = BN * 128;          // one B buffer bytes
  __shared__ __align__(16) char ldsA[2 * 32768];
  __shared__ __align__(16) char ldsB[3 * BBUF];

  const int tid  = threadIdx.x;
  const int w    = tid >> 6, lane = tid & 63;
  const int lane16 = lane & 15, quad = lane >> 4;
  const int wm = w >> 2, wn = w & 3;               // 2(M) x 4(N) wave grid

  // XCD-aware block swizzle (grid is exactly 256 = 8*32 blocks): XCD k owns M-row k
  const int nwg = gridDim.x * gridDim.y;
  int bid = blockIdx.y * gridDim.x + blockIdx.x;
  bid = (bid & 7) * (nwg >> 3) + (bid >> 3);
  const int bx = bid % gridDim.x, by = bid / gridDim.x;
  const int bm = by * 256, bn = bx * BN;

  const int NT = K >> 6;

  // stage full A tile (2048 chunks, 4/thread): row = c>>3, phys slot = c&7,
  // global k-chunk = (c&7) ^ (row&7)
  auto stageA = [&](int buf, int t) {
#pragma unroll
    for (int i = 0; i < 4; ++i) {
      int c = tid + (i << 9);
      int row = c >> 3, sl = c & 7;
      async_copy16(ldsA + buf*32768 + c*16,
                   A + (size_t)(bm + row) * K + t*64 + ((sl ^ (row & 7)) << 3));
    }
  };
  // stage full B tile (BN*8 chunks, BCH/thread)
  auto stageB = [&](int buf, int t) {
#pragma unroll
    for (int i = 0; i < BCH; ++i) {
      int c = tid + (i << 9);
      int col = c >> 3, sl = c & 7;
      async_copy16(ldsB + buf*BBUF + c*16,
                   Bt + (size_t)(bn + col) * K + t*64 + ((sl ^ (col & 7)) << 3));
    }
  };

  f32x4 acc[8][BNF] = {};

#define LD_A(DST, BUF, KS, QM)                                                        \
  do {                                                                                \
    _Pragma("unroll")                                                                 \
    for (int ii = 0; ii < 4; ++ii) {                                                  \
      int row_ = wm*128 + (QM)*64 + ii*16 + lane16;                                   \
      int S_ = ((KS)*4 + quad) ^ (lane16 & 7);                                        \
      (DST)[ii] = *(const bf16x8*)(ldsA + (BUF)*32768 + row_*128 + S_*16);            \
    }                                                                                 \
  } while (0)
#define LD_B(DST, BUF, KS)                                                            \
  do {                                                                                \
    _Pragma("unroll")                                                                 \
    for (int jj = 0; jj < BNF; ++jj) {                                                \
      int col_ = wn*(BN/4) + jj*16 + lane16;                                          \
      int S_ = ((KS)*4 + quad) ^ (lane16 & 7);                                        \
      (DST)[jj] = *(const bf16x8*)(ldsB + (BUF)*BBUF + col_*128 + S_*16);             \
    }                                                                                 \
  } while (0)
#define MMA_BATCH(AF, BF, QM)                                                         \
  do {                                                                                \
    __builtin_amdgcn_s_setprio(1);                                                    \
    _Pragma("unroll")                                                                 \
    for (int jj = 0; jj < BNF; ++jj)                                                  \
      _Pragma("unroll")                                                               \
      for (int ii = 0; ii < 4; ++ii)                                                  \
        acc[(QM)*4 + ii][jj] = __builtin_amdgcn_mfma_f32_16x16x32_bf16(               \
            (AF)[ii], (BF)[jj], acc[(QM)*4 + ii][jj], 0, 0, 0);                       \
    __builtin_amdgcn_s_setprio(0);                                                    \
  } while (0)

  // prologue: order matters for the counted wait: B0, A0, B1, A1 -> keep newest 4+BCH
  stageB(0, 0); stageA(0, 0); stageB(1, 1); stageA(1, 1);
  asm volatile("s_waitcnt vmcnt(%0)" :: "i"(4 + BCH) : "memory");
  block_barrier();

  for (int t = 0; t < NT; ++t) {
    const int ca = t & 1;                 // A buf
    const int cbb = t % 3;                // B buf
    if (t + 2 < NT) stageB((t + 2) % 3, t + 2);   // early: 2-tile distance

    bf16x8 af[4], b0[BNF], b1[BNF];
    LD_B(b0, cbb, 0);
    LD_A(af, ca, 0, 0);
    MMA_BATCH(af, b0, 0);
    LD_A(af, ca, 0, 1);
    MMA_BATCH(af, b0, 1);
    LD_B(b1, cbb, 1);
    LD_A(af, ca, 1, 0);
    MMA_BATCH(af, b1, 0);
    LD_A(af, ca, 1, 1);
    MMA_BATCH(af, b1, 1);

    block_barrier();                      // all tile-t LDS reads complete
    if (t + 2 < NT) {
      stageA(ca, t + 2);                  // late: overwrite A buf just fully read
      asm volatile("s_waitcnt vmcnt(%0)" :: "i"(4 + BCH) : "memory");
    } else {
      asm volatile("s_waitcnt vmcnt(0)" ::: "memory");
    }
    block_barrier();                      // t+1's tiles guaranteed landed for all waves
  }

  // epilogue: C write (+ optional fused RoPE on cols < 5120)
#pragma unroll
  for (int i = 0; i < 8; ++i)
#pragma unroll
    for (int j = 0; j < BNF; ++j) {
      const int colb = bn + wn*(BN/4) + j*16;
      const bool do_rope = ROPE && colb < 5120;          // wave-uniform per j
      const int p2 = (colb + lane16) & 126;              // 2*p within head
#pragma unroll
      for (int r = 0; r < 4; ++r) {
        size_t row = (size_t)bm + wm*128 + i*16 + quad*4 + r;  // C/D: row=quad*4+reg
        size_t col = (size_t)colb + lane16;                    //      col=lane&15
        float v = acc[i][j][r];
        if (ROPE) {
          float vp = __shfl_xor(v, 1);                   // partner feature value
          if (do_rope) {
            float2 cd = *(const float2*)&fr[row*128 + p2];
            v = (lane16 & 1) ? (vp*cd.y + v*cd.x) : (v*cd.x - vp*cd.y);
          }
        }
        if (OUT_F32) ((float*)Cout)[row * N + col] = v;
        else         ((bf16*)Cout)[row * N + col] = (bf16)v;
      }
    }
#undef LD_A
#undef LD_B
#undef MMA_BATCH
}

// ---------------- transpose v slice of qkv -> vt[kv][d][t] ----------------
__global__ __launch_bounds__(256) void transpose_v_kernel(const bf16* __restrict__ qkv,
                                                          bf16* __restrict__ vt) {
  __shared__ bf16 tile[32][33];
  int tt = blockIdx.x * 32;
  int dd = blockIdx.y * 32;
  int kv = blockIdx.z;
  int tx = threadIdx.x & 31, ty = threadIdx.x >> 5;
  const bf16* src = qkv + VOFF + kv * HD;
#pragma unroll
  for (int j = 0; j < 4; ++j)
    tile[ty + j*8][tx] = src[(size_t)(tt + ty + j*8) * QKVN + dd + tx];
  __syncthreads();
  bf16* dst = vt + ((size_t)kv * HD + dd) * SEQ + tt;
#pragma unroll
  for (int j = 0; j < 4; ++j)
    dst[(size_t)(ty + j*8) * SEQ + tx] = tile[tx][ty + j*8];
}

// ---------------- flash attention v3 (unchanged) ----------------
__global__ __launch_bounds__(256, 3) void flash_attn_kernel(const bf16* __restrict__ qkv,
                                                            const bf16* __restrict__ vt,
                                                            bf16* __restrict__ out) {
  __shared__ __align__(16) bf16 Ks[4*96*32];    // [kk=4][kvrow=96][32]   24 KB
  __shared__ __align__(16) bf16 Vts[3*128*32];  // [kk2=3][d=128][32kv]   24 KB
  const int b  = blockIdx.x;                    // 1D, qt-descending for balance
  const int qt = 31 - (b >> 5);
  const int h  = b & 31;
  const int kvh = h >> 2;                       // NREP = 4
  const int tid = threadIdx.x;
  const int w = tid >> 6, lane = tid & 63;
  const int lane16 = lane & 15, quad = lane >> 4;
  const float scale = 0.08838834764831845f;     // 1/sqrt(128)
  const int qglob = qt*64 + w*16 + lane16;      // this lane's q column

  const bf16* qrow = qkv + (size_t)qglob * QKVN + h * HD + quad*8;
  bf16x8 qreg[4];
#pragma unroll
  for (int kk = 0; kk < 4; ++kk)
    qreg[kk] = *(const bf16x8*)(qrow + kk*32);

  f32x4 acc_o[8] = {};                          // [jd][reg]: row q=quad*4+reg, col d=jd*16+lane16
  float m_s = -3e38f, l_s = 0.f;                // scalar per lane (column q)

  const bf16* kbase0 = qkv + KOFF + kvh * HD;
  const bf16* vbase0 = vt + (size_t)kvh * HD * SEQ;

  const int L = (qt*64 + 159) / 96;             // ceil((qt+1)*64 / 96) kv tiles
  for (int jj = 0; jj < L; ++jj) {
    const int kv0 = jj * 96;
    __syncthreads();                            // prior iter's ds_reads done before restage
#pragma unroll
    for (int i = 0; i < 6; ++i) {               // 1536 chunks each for K and Vt
      int c = tid + i * 256;
      {
        int kk = c / 384, rem = c - kk*384;     // K: [kk][kvrow][32]
        async_copy16(&Ks[c*8], kbase0 + (size_t)(kv0 + (rem >> 2)) * QKVN + kk*32 + (rem & 3) * 8);
      }
      {
        int kk2 = c >> 9, cp = c & 511;         // Vt: [kk2][d][32kv]
        async_copy16(&Vts[c*8], vbase0 + (size_t)(cp >> 2) * SEQ + kv0 + kk2*32 + (cp & 3) * 8);
      }
    }
    __syncthreads();                            // drains staging

    // S^T = K Q^T : A=K rows (m=kv), B=Q rows (n=q). acc row=kv local, col=q.
    f32x4 accT[6] = {};
#pragma unroll
    for (int kk = 0; kk < 4; ++kk)
#pragma unroll
      for (int jn = 0; jn < 6; ++jn) {
        bf16x8 kf = *(const bf16x8*)&Ks[(kk*96 + jn*16 + lane16)*32 + quad*8];
        accT[jn] = __builtin_amdgcn_mfma_f32_16x16x32_bf16(kf, qreg[kk], accT[jn], 0, 0, 0);
      }

    float s[6][4];
#pragma unroll
    for (int jn = 0; jn < 6; ++jn)
#pragma unroll
      for (int r = 0; r < 4; ++r) {
        float v = accT[jn][r] * scale;
        if ((kv0 + jn*16 + quad*4 + r) > qglob) v = -3e38f;
        s[jn][r] = v;
      }

    float mt = s[0][0];
#pragma unroll
    for (int jn = 0; jn < 6; ++jn)
#pragma unroll
      for (int r = 0; r < 4; ++r) mt = fmaxf(mt, s[jn][r]);
    mt = fmaxf(mt, __shfl_xor(mt, 16));
    mt = fmaxf(mt, __shfl_xor(mt, 32));
    float mnew = fmaxf(m_s, mt);
    float alpha = __expf(m_s - mnew);
    m_s = mnew;
    float rs = 0.f;
#pragma unroll
    for (int jn = 0; jn < 6; ++jn)
#pragma unroll
      for (int r = 0; r < 4; ++r) {
        float p = __expf(s[jn][r] - mnew);
        s[jn][r] = p;
        rs += p;
      }
    rs += __shfl_xor(rs, 16);
    rs += __shfl_xor(rs, 32);
    l_s = l_s * alpha + rs;

    float alpha_row[4];
#pragma unroll
    for (int r = 0; r < 4; ++r)
      alpha_row[r] = __shfl(alpha, quad*4 + r);
#pragma unroll
    for (int jd = 0; jd < 8; ++jd)
#pragma unroll
      for (int r = 0; r < 4; ++r) acc_o[jd][r] *= alpha_row[r];

    uint32_t pk[6][2];
#pragma unroll
    for (int jn = 0; jn < 6; ++jn) {
      pk[jn][0] = pack2bf(s[jn][0], s[jn][1]);
      pk[jn][1] = pack2bf(s[jn][2], s[jn][3]);
    }

    const int src0 = (quad & 1) * 32 + lane16;
    const int src1 = src0 + 16;
    const bool hi = quad >= 2;
#pragma unroll
    for (int kk2 = 0; kk2 < 3; ++kk2) {
      uint32_t v0l = __shfl(pk[2*kk2][0],   src0), v0h = __shfl(pk[2*kk2][1],   src0);
      uint32_t v1l = __shfl(pk[2*kk2][0],   src1), v1h = __shfl(pk[2*kk2][1],   src1);
      uint32_t w0l = __shfl(pk[2*kk2+1][0], src0), w0h = __shfl(pk[2*kk2+1][1], src0);
      uint32_t w1l = __shfl(pk[2*kk2+1][0], src1), w1h = __shfl(pk[2*kk2+1][1], src1);
      union { uint32_t u[4]; bf16x8 v; } af;
      af.u[0] = hi ? w0l : v0l;
      af.u[1] = hi ? w0h : v0h;
      af.u[2] = hi ? w1l : v1l;
      af.u[3] = hi ? w1h : v1h;
#pragma unroll
      for (int jd = 0; jd < 8; ++jd) {
        bf16x8 vf = *(const bf16x8*)&Vts[(kk2*128 + jd*16 + lane16)*32 + quad*8];
        acc_o[jd] = __builtin_amdgcn_mfma_f32_16x16x32_bf16(af.v, vf, acc_o[jd], 0, 0, 0);
      }
    }
  }

  const float inv_l = 1.f / l_s;
  float linv[4];
#pragma unroll
  for (int r = 0; r < 4; ++r)
    linv[r] = __shfl(inv_l, quad*4 + r);

  bf16* obase = out + (size_t)(qt*64 + w*16) * DIM + h * HD;
#pragma unroll
  for (int jd = 0; jd < 8; ++jd)
#pragma unroll
    for (int r = 0; r < 4; ++r)
      obase[(size_t)(quad*4 + r) * DIM + jd*16 + lane16] = (bf16)(acc_o[jd][r] * linv[r]);
}

extern "C" void kernel_launch(void* const* d_in, const int* in_sizes, int n_in,
                              void* d_out, int out_size, void* d_ws, size_t ws_size,
                              hipStream_t stream) {
  const float* x  = (const float*)d_in[0];
  // d_in[1] = cache_kv: dead (start_pos=0, L=SEQ -> keys/values == xk/xv)
  const float* fr = (const float*)d_in[2];
  const float* wq = (const float*)d_in[3];
  const float* wk = (const float*)d_in[4];
  const float* wv = (const float*)d_in[5];
  const float* wo = (const float*)d_in[6];
  // d_in[7] = start_pos = 0
  float* out = (float*)d_out;

  char* ws = (char*)d_ws;
  bf16* xb     = (bf16*)(ws);                    // 2048x4096          16,777,216 B
  bf16* wqkv_t = (bf16*)(ws + 16777216);         // 6144x4096 (N,K)   50,331,648 B
  bf16* wo_t   = (bf16*)(ws + 67108864);         // 4096x4096 (N,K)   33,554,432 B
  bf16* qkv    = (bf16*)(ws + 100663296);        // 2048x6144         25,165,824 B
  bf16* vt     = (bf16*)(ws + 125829120);        // 8x128x2048         4,194,304 B
  bf16* attn   = (bf16*)(ws + 130023424);        // 2048x4096         16,777,216 B
  (void)ws_size; (void)in_sizes; (void)n_in; (void)out_size;

  cast_x_kernel<<<8192, 256, 0, stream>>>(x, xb);
  transpose_cast_kernel<<<dim3(64,64), 256, 0, stream>>>(wq, wqkv_t, DIM, DIM);
  transpose_cast_kernel<<<dim3(16,64), 256, 0, stream>>>(wk, wqkv_t + (size_t)4096*4096, DIM, 1024);
  transpose_cast_kernel<<<dim3(16,64), 256, 0, stream>>>(wv, wqkv_t + (size_t)5120*4096, DIM, 1024);
  transpose_cast_kernel<<<dim3(64,64), 256, 0, stream>>>(wo, wo_t, DIM, DIM);

  gemm256_kernel<0,1,192><<<dim3(32,8), 512, 0, stream>>>(xb, wqkv_t, qkv, SEQ, QKVN, DIM, fr);
  transpose_v_kernel<<<dim3(64,4,8), 256, 0, stream>>>(qkv, vt);
  flash_attn_kernel<<<1024, 256, 0, stream>>>(qkv, vt, attn);
  gemm256_kernel<1,0,128><<<dim3(32,8), 512, 0, stream>>>(attn, wo_t, out, SEQ, DIM, DIM, nullptr);
}